// Round 1
// baseline (116.723 us; speedup 1.0000x reference)
//
#include <hip/hip_runtime.h>
#include <math.h>

#define N_TOK 8192
#define DDIM  768
#define NEXP  16

// Output layout (floats), concatenated in reference return order:
// y[N,D] | soft_avg[16] | hard_avg[16] | s_concat[N,16] | scalar 0
#define SOFT_OFF (N_TOK*DDIM)
#define HARD_OFF (SOFT_OFF + NEXP)
#define S_OFF    (HARD_OFF + NEXP)
#define SCAL_OFF (S_OFF + N_TOK*NEXP)

extern "C" __global__ void init_out_kernel(float* __restrict__ out) {
  int t = threadIdx.x;
  if (t < 2*NEXP) out[SOFT_OFF + t] = 0.0f;  // zero soft+hard accumulators
  if (t == 0) out[SCAL_OFF] = 0.0f;          // the trailing scalar 0
}

__device__ __forceinline__ void fma4(float4& a, float s, float4 w) {
  a.x = fmaf(s, w.x, a.x);
  a.y = fmaf(s, w.y, a.y);
  a.z = fmaf(s, w.z, a.z);
  a.w = fmaf(s, w.w, a.w);
}

__device__ __forceinline__ void xred(float& v) {
  // reduce across the 16 d-chunks: c lives in lane bits 2..5
  v += __shfl_xor(v, 4);
  v += __shfl_xor(v, 8);
  v += __shfl_xor(v, 16);
  v += __shfl_xor(v, 32);
}

__device__ __forceinline__ void finish_token(
    int n, float4 av, int lane, float* __restrict__ out,
    float4* __restrict__ table, float* s_soft, float* s_hard) {
  // gather all 16 logits (lane q<4 has expert quad 4q..4q+3); uniform result
  float v[16];
  #pragma unroll
  for (int q = 0; q < 4; ++q) {
    v[q*4+0] = __shfl(av.x, q);
    v[q*4+1] = __shfl(av.y, q);
    v[q*4+2] = __shfl(av.z, q);
    v[q*4+3] = __shfl(av.w, q);
  }
  // top-2, stable (strict > keeps lowest index on ties, matching lax.top_k)
  float v0 = -INFINITY, v1 = -INFINITY;
  int e0 = 0, e1 = 0;
  #pragma unroll
  for (int j = 0; j < 16; ++j) {
    float val = v[j];
    if (val > v0) { v1 = v0; e1 = e0; v0 = val; e0 = j; }
    else if (val > v1) { v1 = val; e1 = j; }
  }
  // softmax over [v0, v1] with max-subtraction: w0 = 1/(1+t), w1 = t/(1+t)
  float t1 = expf(v1 - v0);
  float inv = 1.0f / (1.0f + t1);
  float w0 = inv;
  float w1 = t1 * inv;
  if (lane == 0) {
    table[n] = make_float4(__int_as_float(e0), __int_as_float(e1), w0, w1);
  }
  if (lane < NEXP) {
    float g = (lane == e0) ? w0 : ((lane == e1) ? w1 : 0.0f);
    bool sel = (g >= 1e-5f);                          // g < eps -> s = 1
    out[S_OFF + (size_t)n*NEXP + lane] = sel ? 0.0f : 1.0f;
    atomicAdd(&s_soft[lane], g);
    if (sel) atomicAdd(&s_hard[lane], 1.0f);
  }
}

extern "C" __global__ __launch_bounds__(256) void gate_kernel(
    const float* __restrict__ x, const float* __restrict__ W,
    const float* __restrict__ bias, float* __restrict__ out,
    float4* __restrict__ table) {
  __shared__ float Wl[DDIM*NEXP];   // [d][e] so 4 experts are a contiguous float4
  __shared__ float s_soft[NEXP];
  __shared__ float s_hard[NEXP];
  int tid = threadIdx.x;
  if (tid < NEXP) { s_soft[tid] = 0.0f; s_hard[tid] = 0.0f; }
  for (int idx = tid; idx < DDIM*NEXP; idx += 256) {
    int d = idx >> 4, e = idx & 15;
    Wl[idx] = W[e*DDIM + d];        // transpose W into LDS
  }
  __syncthreads();

  int wave = tid >> 6;
  int lane = tid & 63;
  int e4 = lane & 3;                // expert quad 0..3
  int c  = lane >> 2;               // d-chunk 0..15 (48 d's each)
  float4 bq = ((const float4*)bias)[e4];

  #pragma unroll
  for (int p = 0; p < 2; ++p) {
    int pairi = (blockIdx.x*4 + wave) + p*2048;   // 512 blocks * 4 waves * 2
    int n0 = pairi*2, n1 = n0 + 1;                // 2 tokens share W reads
    const float* x0p = x + (size_t)n0*DDIM + c*48;
    const float* x1p = x + (size_t)n1*DDIM + c*48;
    const float* wbase = &Wl[c*48*16 + 4*e4];
    float4 a0 = make_float4(0.f,0.f,0.f,0.f);
    float4 a1 = make_float4(0.f,0.f,0.f,0.f);
    #pragma unroll
    for (int m = 0; m < 12; ++m) {
      float4 xv0 = *(const float4*)(x0p + 4*m);
      float4 xv1 = *(const float4*)(x1p + 4*m);
      const float* wb = wbase + m*64;
      float4 wq0 = *(const float4*)(wb);
      float4 wq1 = *(const float4*)(wb + 16);
      float4 wq2 = *(const float4*)(wb + 32);
      float4 wq3 = *(const float4*)(wb + 48);
      fma4(a0, xv0.x, wq0); fma4(a0, xv0.y, wq1);
      fma4(a0, xv0.z, wq2); fma4(a0, xv0.w, wq3);
      fma4(a1, xv1.x, wq0); fma4(a1, xv1.y, wq1);
      fma4(a1, xv1.z, wq2); fma4(a1, xv1.w, wq3);
    }
    xred(a0.x); xred(a0.y); xred(a0.z); xred(a0.w);
    xred(a1.x); xred(a1.y); xred(a1.z); xred(a1.w);
    a0.x += bq.x; a0.y += bq.y; a0.z += bq.z; a0.w += bq.w;
    a1.x += bq.x; a1.y += bq.y; a1.z += bq.z; a1.w += bq.w;
    finish_token(n0, a0, lane, out, table, s_soft, s_hard);
    finish_token(n1, a1, lane, out, table, s_soft, s_hard);
  }
  __syncthreads();
  if (tid < NEXP) {
    atomicAdd(&out[SOFT_OFF + tid], s_soft[tid] * (1.0f/N_TOK));
    atomicAdd(&out[HARD_OFF + tid], s_hard[tid] * (1.0f/N_TOK));
  }
}

extern "C" __global__ __launch_bounds__(256) void combine_kernel(
    const float* __restrict__ f, const float4* __restrict__ table,
    float* __restrict__ y) {
  int n = blockIdx.x;
  float4 rec = table[n];
  int e0 = __float_as_int(rec.x);
  int e1 = __float_as_int(rec.y);
  float w0 = rec.z, w1 = rec.w;
  int tid = threadIdx.x;
  // each thread owns expert sub-quad (tid&3)*4 .. +3 of the 16-expert axis
  int jg = (tid & 3) * 4;
  float4 gq;
  gq.x = (jg+0 == e0) ? w0 : ((jg+0 == e1) ? w1 : 0.0f);
  gq.y = (jg+1 == e0) ? w0 : ((jg+1 == e1) ? w1 : 0.0f);
  gq.z = (jg+2 == e0) ? w0 : ((jg+2 == e1) ? w1 : 0.0f);
  gq.w = (jg+3 == e0) ? w0 : ((jg+3 == e1) ? w1 : 0.0f);
  const float4* fp = (const float4*)(f + (size_t)n * (DDIM*NEXP));
  float* yr = y + (size_t)n * DDIM;
  // 3072 float4 per token / 256 threads = 12 fully-coalesced 1KiB wave loads
  #pragma unroll
  for (int k = 0; k < 12; ++k) {
    int q = tid + 256*k;
    float4 v = fp[q];
    float part = v.x*gq.x + v.y*gq.y + v.z*gq.z + v.w*gq.w;
    part += __shfl_xor(part, 1);     // 4 consecutive lanes share one d
    part += __shfl_xor(part, 2);
    if ((tid & 3) == 0) yr[q >> 2] = part;
  }
}

extern "C" void kernel_launch(void* const* d_in, const int* in_sizes, int n_in,
                              void* d_out, int out_size, void* d_ws, size_t ws_size,
                              hipStream_t stream) {
  const float* f = (const float*)d_in[0];   // [N, D, E]
  const float* x = (const float*)d_in[1];   // [N, D]
  const float* W = (const float*)d_in[2];   // [E, D]
  const float* b = (const float*)d_in[3];   // [E]
  float* out = (float*)d_out;
  float4* table = (float4*)d_ws;            // per-token {e0, e1, w0, w1}

  hipLaunchKernelGGL(init_out_kernel, dim3(1), dim3(64), 0, stream, out);
  hipLaunchKernelGGL(gate_kernel, dim3(512), dim3(256), 0, stream,
                     x, W, b, out, table);
  hipLaunchKernelGGL(combine_kernel, dim3(N_TOK), dim3(256), 0, stream,
                     f, table, out /* y at offset 0 */);
}